// Round 11
// baseline (187.167 us; speedup 1.0000x reference)
//
#include <hip/hip_runtime.h>

// ---------------------------------------------------------------------------
// MultiHeadAttention — fp32 in/out, bf16 compute.
// Round 21: (1) flash_attn merged to ONE 512-thread block per (bh, 256-q)
// (grid 256, 8 waves = 2/SIMD, same occupancy as 2x256-thr blocks) -> per-CU
// LDS traffic -13% (stage writes + Mb + Q setup done once per CU-tile instead
// of twice). r10 counters: flash DS pipe ~31us > MFMA 16 > VALU 18 ->
// LDS-bandwidth-bound; this cuts the only reducible DS term w/o occupancy
// loss. Body = proven r12 pipeline; staging extended to a0 in [0,64) with
// krow0's +32 bit explicit. (2) gemm_o ported to r20-proven 256x64 4-phase
// (8 waves of 64x32, B-hoist, counted-stage QITER). qkv/conv unchanged (r20).
// BS=2, QLEN=2048, DIM=1024, NH=16, DH=64.
// d_out (16 MB fp32): [ Q_bf16 8MB | X_bf16 8MB ]  (dead before O-GEMM writes)
// d_ws  (>=32MB):     [ K_bf16 8MB | C_bf16 8MB | Vt 8MB | W_bf16 8MB ]
// ---------------------------------------------------------------------------

#define BS    2
#define QLEN  2048
#define DIM   1024
#define NH    16
#define DH    64
#define MTOK  (BS * QLEN)          // 4096 token rows

// Q projection scale: (1/8) * log2(e) so attention uses exp2 directly.
#define QSCALE 0.18033688011112042f

typedef __attribute__((ext_vector_type(8))) short short8;   // 8 bf16
typedef __attribute__((ext_vector_type(4))) float float4_t; // MFMA acc
typedef __attribute__((ext_vector_type(4))) int   int4_t;

__device__ __forceinline__ ushort f2bf(float f) {   // RNE
    unsigned u = __float_as_uint(f);
    return (ushort)((u + 0x7fffu + ((u >> 16) & 1u)) >> 16);
}
__device__ __forceinline__ short8 pack8(float4 a0, float4 a1) {
    short8 r;
    r[0] = (short)f2bf(a0.x); r[1] = (short)f2bf(a0.y);
    r[2] = (short)f2bf(a0.z); r[3] = (short)f2bf(a0.w);
    r[4] = (short)f2bf(a1.x); r[5] = (short)f2bf(a1.y);
    r[6] = (short)f2bf(a1.z); r[7] = (short)f2bf(a1.w);
    return r;
}

// async global->LDS, 16 B per lane (lds dest = wave-uniform base + lane*16).
__device__ __forceinline__ void glds16(const void* g, void* l) {
    __builtin_amdgcn_global_load_lds(
        (const __attribute__((address_space(1))) unsigned int*)g,
        (__attribute__((address_space(3))) unsigned int*)l, 16, 0, 0);
}

// ---------------------------------------------------------------------------
// Combined fp32 -> bf16 convert: X (4M) + 4 weights (1M each), one launch.
// ---------------------------------------------------------------------------
__global__ __launch_bounds__(256) void conv_all(
    const float* __restrict__ x,  const float* __restrict__ qw,
    const float* __restrict__ kw, const float* __restrict__ vw,
    const float* __restrict__ ow,
    ushort* __restrict__ Xbf, ushort* __restrict__ Wbf)
{
    const int blk = blockIdx.x;
    const float* s; ushort* d; size_t base;
    if (blk < 4096)      { s = x;  d = Xbf;             base = (size_t)blk * 1024; }
    else if (blk < 5120) { s = qw; d = Wbf;             base = (size_t)(blk - 4096) * 1024; }
    else if (blk < 6144) { s = kw; d = Wbf + 1048576;   base = (size_t)(blk - 5120) * 1024; }
    else if (blk < 7168) { s = vw; d = Wbf + 2097152;   base = (size_t)(blk - 6144) * 1024; }
    else                 { s = ow; d = Wbf + 3145728;   base = (size_t)(blk - 7168) * 1024; }
    const size_t i = base + threadIdx.x * 4;
    float4 v = *(const float4*)(s + i);
    ushort4 o;
    o.x = f2bf(v.x); o.y = f2bf(v.y); o.z = f2bf(v.z); o.w = f2bf(v.w);
    *(ushort4*)(d + i) = o;
}

// ---------------------------------------------------------------------------
// V transpose (FALLBACK PATH ONLY)
// ---------------------------------------------------------------------------
__global__ __launch_bounds__(256) void transpose_v(
    const ushort* __restrict__ Vrow, ushort* __restrict__ Vt)
{
    __shared__ ushort T[64][72];
    const int tid  = threadIdx.x;
    const int tile = blockIdx.x;
    const int bh   = blockIdx.y;
    const int b = bh >> 4, h = bh & 15;

    #pragma unroll
    for (int rep = 0; rep < 2; ++rep) {
        int ch = tid + rep * 256;
        int tok = ch >> 3, seg = ch & 7;
        uint4 v = *(const uint4*)(Vrow + (size_t)(b * QLEN + tile * 64 + tok) * DIM
                                        + h * DH + seg * 8);
        *(uint4*)&T[tok][seg * 8] = v;
    }
    __syncthreads();
    #pragma unroll
    for (int rep = 0; rep < 2; ++rep) {
        int ch = tid + rep * 256;
        int dim = ch >> 3, tseg = ch & 7;
        ushort t0 = T[tseg * 8 + 0][dim], t1 = T[tseg * 8 + 1][dim];
        ushort t2 = T[tseg * 8 + 2][dim], t3 = T[tseg * 8 + 3][dim];
        ushort t4 = T[tseg * 8 + 4][dim], t5 = T[tseg * 8 + 5][dim];
        ushort t6 = T[tseg * 8 + 6][dim], t7 = T[tseg * 8 + 7][dim];
        uint4 o;
        o.x = (unsigned)t0 | ((unsigned)t1 << 16);
        o.y = (unsigned)t2 | ((unsigned)t3 << 16);
        o.z = (unsigned)t4 | ((unsigned)t5 << 16);
        o.w = (unsigned)t6 | ((unsigned)t7 << 16);
        *(uint4*)(Vt + (size_t)bh * DH * QLEN + (size_t)dim * QLEN
                      + tile * 64 + tseg * 8) = o;
    }
}

// ---------------------------------------------------------------------------
// QKV GEMM — 256x192 tile, BK=64, 4-phase schedule, B-frag hoisting.
// (unchanged from r20)
// ---------------------------------------------------------------------------
__global__ __launch_bounds__(512, 2) void gemm_qkv(
    const ushort* __restrict__ A, const ushort* __restrict__ Bw,
    const float* __restrict__ bias0, const float* __restrict__ bias1,
    const float* __restrict__ bias2,
    ushort* __restrict__ outQ, ushort* __restrict__ outK, ushort* __restrict__ outVt)
{
    __shared__ ushort As[2][256 * 64];   // 32KB per buf
    __shared__ ushort Bs[2][192 * 64];   // 24KB per buf

    const int tid  = threadIdx.x;          // 0..511
    const int w    = tid >> 6;             // 0..7
    const int lane = tid & 63;
    const int r15  = lane & 15;
    const int quad = lane >> 4;
    const int wm   = w >> 2;               // 0..1 (M half, 128 rows)
    const int wn   = w & 3;                // 0..3 (N block, 48 cols)
    const int xg   = r15 & 7;

    const int xcd = blockIdx.x & 7;
    const int lid = blockIdx.x >> 3;               // 0..31
    const int brow = (xcd & 3) * 4 + (lid & 3);    // 0..15
    const int bcol = (xcd >> 2) * 8 + (lid >> 2);  // 0..15
    const int K = DIM;

    float4_t acc[8][3];
    #pragma unroll
    for (int i = 0; i < 8; ++i)
        #pragma unroll
        for (int j = 0; j < 3; ++j)
            acc[i][j] = (float4_t){0.f, 0.f, 0.f, 0.f};

    const ushort* gaS[4];
    const ushort* gbS[3];
    #pragma unroll
    for (int rep = 0; rep < 4; ++rep) {
        const int c   = rep * 512 + tid;           // 0..2047
        const int row = c >> 3;                    // 0..255
        const int g   = (c & 7) ^ (row & 7);
        gaS[rep] = A + (size_t)(brow * 256 + row) * K + g * 8;
    }
    #pragma unroll
    for (int rep = 0; rep < 3; ++rep) {
        const int c   = rep * 512 + tid;           // 0..1535
        const int row = c >> 3;                    // 0..191
        const int g   = (c & 7) ^ (row & 7);
        gbS[rep] = Bw + (size_t)(bcol * 192 + row) * K + g * 8;
    }

    short8 afr[2][4];
    short8 bfr[2][3];

#define QBAR() do { asm volatile("" ::: "memory");                            \
                    __builtin_amdgcn_s_barrier();                             \
                    asm volatile("" ::: "memory"); } while (0)
#define QVM0() asm volatile("s_waitcnt vmcnt(0)" ::: "memory")

#define STAGE_T(BUFI, KOFF) do {                                              \
    _Pragma("unroll")                                                         \
    for (int rep = 0; rep < 4; ++rep)                                         \
        glds16(gaS[rep] + (KOFF), &As[BUFI][(rep * 512 + tid) * 8]);          \
    _Pragma("unroll")                                                         \
    for (int rep = 0; rep < 3; ++rep)                                         \
        glds16(gbS[rep] + (KOFF), &Bs[BUFI][(rep * 512 + tid) * 8]);          \
} while (0)

#define PH_B(BUFI) do {                                                       \
    _Pragma("unroll")                                                         \
    for (int hh = 0; hh < 2; ++hh) {                                          \
        const int ph = ((hh * 4 + quad) ^ xg) * 8;                            \
        _Pragma("unroll")                                                     \
        for (int ns = 0; ns < 3; ++ns)                                        \
            bfr[hh][ns] = *(const short8*)&Bs[BUFI][(wn * 48 + ns * 16 + r15) * 64 + ph]; \
    }                                                                         \
} while (0)

#define PH_A(BUFI, MH) do {                                                   \
    const int arow0 = wm * 128 + (MH) * 64;                                   \
    _Pragma("unroll")                                                         \
    for (int hh = 0; hh < 2; ++hh) {                                          \
        const int ph = ((hh * 4 + quad) ^ xg) * 8;                            \
        _Pragma("unroll")                                                     \
        for (int ms = 0; ms < 4; ++ms)                                        \
            afr[hh][ms] = *(const short8*)&As[BUFI][(arow0 + ms * 16 + r15) * 64 + ph]; \
    }                                                                         \
} while (0)

#define MFMA_MH(MH) do {                                                      \
    __builtin_amdgcn_s_setprio(1);                                            \
    _Pragma("unroll")                                                         \
    for (int hh = 0; hh < 2; ++hh)                                            \
        _Pragma("unroll")                                                     \
        for (int ms = 0; ms < 4; ++ms)                                        \
            _Pragma("unroll")                                                 \
            for (int ns = 0; ns < 3; ++ns)                                    \
                acc[(MH) * 4 + ms][ns] =                                      \
                    __builtin_amdgcn_mfma_f32_16x16x32_bf16(                  \
                        afr[hh][ms], bfr[hh][ns], acc[(MH) * 4 + ms][ns], 0, 0, 0); \
    __builtin_amdgcn_s_setprio(0);                                            \
} while (0)

#define QITER(KB, LAST) do {                                                  \
    STAGE_T(1, (KB) + 64);                                                    \
    PH_B(0); PH_A(0, 0); MFMA_MH(0);                 QBAR();                  \
    PH_A(0, 1); MFMA_MH(1); QVM0();                  QBAR();                  \
    if (!(LAST)) STAGE_T(0, (KB) + 128);                                      \
    PH_B(1); PH_A(1, 0); MFMA_MH(0);                 QBAR();                  \
    PH_A(1, 1); MFMA_MH(1); if (!(LAST)) { QVM0(); } QBAR();                  \
} while (0)

    STAGE_T(0, 0);
    QVM0();
    QBAR();

    for (int i = 0; i < 7; ++i)
        QITER(i * 128, 0);
    QITER(896, 1);

#undef QITER
#undef MFMA_MH
#undef PH_A
#undef PH_B
#undef STAGE_T
#undef QVM0
#undef QBAR

    #pragma unroll
    for (int msg = 0; msg < 8; ++msg) {
        const int rowg = brow * 256 + wm * 128 + msg * 16 + quad * 4;  // token
        #pragma unroll
        for (int nsg = 0; nsg < 3; ++nsg) {
            const int colg = bcol * 192 + wn * 48 + nsg * 16 + r15;
            if (colg < 1024) {
                const float bb = bias0[colg];
                #pragma unroll
                for (int r = 0; r < 4; ++r)
                    outQ[(size_t)(rowg + r) * 1024 + colg] =
                        f2bf((acc[msg][nsg][r] + bb) * QSCALE);
            } else if (colg < 2048) {
                const float bb = bias1[colg - 1024];
                #pragma unroll
                for (int r = 0; r < 4; ++r)
                    outK[(size_t)(rowg + r) * 1024 + (colg - 1024)] =
                        f2bf(acc[msg][nsg][r] + bb);
            } else {
                const int vcol = colg - 2048;
                const int hh2 = vcol >> 6, dd = vcol & 63;
                const float bb = bias2[vcol];
                const int bidx = rowg >> 11;
                const int tloc = rowg & 2047;
                ushort4 o4;
                o4.x = f2bf(acc[msg][nsg][0] + bb);
                o4.y = f2bf(acc[msg][nsg][1] + bb);
                o4.z = f2bf(acc[msg][nsg][2] + bb);
                o4.w = f2bf(acc[msg][nsg][3] + bb);
                *(ushort4*)&outVt[((size_t)(bidx * 16 + hh2) * 64 + dd) * QLEN + tloc] = o4;
            }
        }
    }
}

// ---------------------------------------------------------------------------
// O-projection GEMM — r21: 256x64 tile, BK=64, 4-phase (r20-proven QITER),
// 8 waves of 64x32, B-frag hoisting. 256 blocks x 512 thr.
// ---------------------------------------------------------------------------
__global__ __launch_bounds__(512, 2) void gemm_o(
    const ushort* __restrict__ A, const ushort* __restrict__ Bw,
    const float* __restrict__ bias, float* __restrict__ Out)
{
    __shared__ ushort As[2][256 * 64];   // 32KB per buf
    __shared__ ushort Bs[2][64 * 64];    // 8KB per buf

    const int tid  = threadIdx.x;          // 0..511
    const int w    = tid >> 6;             // 0..7
    const int lane = tid & 63;
    const int r15  = lane & 15;
    const int quad = lane >> 4;
    const int wm   = w >> 1;               // 0..3 (64-row block)
    const int wn   = w & 1;                // 0..1 (32-col block)
    const int xg   = r15 & 7;

    const int xcd = blockIdx.x & 7;
    const int lid = blockIdx.x >> 3;               // 0..31
    const int brow = (xcd & 3) * 4 + (lid & 3);    // 0..15
    const int bcol = (xcd >> 2) * 8 + (lid >> 2);  // 0..15
    const int K = DIM;

    float4_t acc[4][2];
    #pragma unroll
    for (int i = 0; i < 4; ++i)
        #pragma unroll
        for (int j = 0; j < 2; ++j)
            acc[i][j] = (float4_t){0.f, 0.f, 0.f, 0.f};

    const ushort* gaS[4];
    #pragma unroll
    for (int rep = 0; rep < 4; ++rep) {
        const int c   = rep * 512 + tid;           // 0..2047
        const int row = c >> 3;                    // 0..255
        const int g   = (c & 7) ^ (row & 7);
        gaS[rep] = A + (size_t)(brow * 256 + row) * K + g * 8;
    }
    const ushort* gbS;
    {
        const int row = tid >> 3;                  // 0..63
        const int g   = (tid & 7) ^ (row & 7);
        gbS = Bw + (size_t)(bcol * 64 + row) * K + g * 8;
    }

    short8 afr[2][2];   // [hh][ms in pair]
    short8 bfr[2][2];   // [hh][ns], hoisted per K-tile

#define OBAR() do { asm volatile("" ::: "memory");                            \
                    __builtin_amdgcn_s_barrier();                             \
                    asm volatile("" ::: "memory"); } while (0)
#define OVM0() asm volatile("s_waitcnt vmcnt(0)" ::: "memory")

#define OSTAGE(BUFI, KOFF) do {                                               \
    _Pragma("unroll")                                                         \
    for (int rep = 0; rep < 4; ++rep)                                         \
        glds16(gaS[rep] + (KOFF), &As[BUFI][(rep * 512 + tid) * 8]);          \
    glds16(gbS + (KOFF), &Bs[BUFI][tid * 8]);                                 \
} while (0)

#define OPH_B(BUFI) do {                                                      \
    _Pragma("unroll")                                                         \
    for (int hh = 0; hh < 2; ++hh) {                                          \
        const int ph = ((hh * 4 + quad) ^ xg) * 8;                            \
        _Pragma("unroll")                                                     \
        for (int ns = 0; ns < 2; ++ns)                                        \
            bfr[hh][ns] = *(const short8*)&Bs[BUFI][(wn * 32 + ns * 16 + r15) * 64 + ph]; \
    }                                                                         \
} while (0)

#define OPH_A(BUFI, MH) do {                                                  \
    const int arow0 = wm * 64 + (MH) * 32;                                    \
    _Pragma("unroll")                                                         \
    for (int hh = 0; hh < 2; ++hh) {                                          \
        const int ph = ((hh * 4 + quad) ^ xg) * 8;                            \
        _Pragma("unroll")                                                     \
        for (int ms = 0; ms < 2; ++ms)                                        \
            afr[hh][ms] = *(const short8*)&As[BUFI][(arow0 + ms * 16 + r15) * 64 + ph]; \
    }                                                                         \
} while (0)

#define OMFMA(MH) do {                                                        \
    __builtin_amdgcn_s_setprio(1);                                            \
    _Pragma("unroll")                                                         \
    for (int hh = 0; hh < 2; ++hh)                                            \
        _Pragma("unroll")                                                     \
        for (int ms = 0; ms < 2; ++ms)                                        \
            _Pragma("unroll")                                                 \
            for (int ns = 0; ns < 2; ++ns)                                    \
                acc[(MH) * 2 + ms][ns] =                                      \
                    __builtin_amdgcn_mfma_f32_16x16x32_bf16(                  \
                        afr[hh][ms], bfr[hh][ns], acc[(MH) * 2 + ms][ns], 0, 0, 0); \
    __builtin_amdgcn_s_setprio(0);                                            \
} while (0)

#define OITER(KB, LAST) do {                                                  \
    OSTAGE(1, (KB) + 64);                                                     \
    OPH_B(0); OPH_A(0, 0); OMFMA(0);                 OBAR();                  \
    OPH_A(0, 1); OMFMA(1); OVM0();                   OBAR();                  \
    if (!(LAST)) OSTAGE(0, (KB) + 128);                                       \
    OPH_B(1); OPH_A(1, 0); OMFMA(0);                 OBAR();                  \
    OPH_A(1, 1); OMFMA(1); if (!(LAST)) { OVM0(); }  OBAR();                  \
} while (0)

    OSTAGE(0, 0);
    OVM0();
    OBAR();

    for (int i = 0; i < 7; ++i)
        OITER(i * 128, 0);
    OITER(896, 1);

#undef OITER
#undef OMFMA
#undef OPH_A
#undef OPH_B
#undef OSTAGE
#undef OVM0
#undef OBAR

    #pragma unroll
    for (int msg = 0; msg < 4; ++msg) {
        const int rowg = brow * 256 + wm * 64 + msg * 16 + quad * 4;
        #pragma unroll
        for (int nsg = 0; nsg < 2; ++nsg) {
            const int colg = bcol * 64 + wn * 32 + nsg * 16 + r15;
            const float bb = bias[colg];
            #pragma unroll
            for (int r = 0; r < 4; ++r)
                Out[(size_t)(rowg + r) * 1024 + colg] = acc[msg][nsg][r] + bb;
        }
    }
}

// ---------------------------------------------------------------------------
// Fallback GEMMs (fp32 inputs, 16x16/wave) for ws_size < 32MB.
// ---------------------------------------------------------------------------
__global__ __launch_bounds__(256) void gemm_f32in_bf16out(
    const float* __restrict__ X, const float* __restrict__ W,
    const float* __restrict__ B, ushort* __restrict__ Out,
    int M, int N, int K, float scale)
{
    const int lane = threadIdx.x & 63;
    const int wid  = (blockIdx.x * blockDim.x + threadIdx.x) >> 6;
    const int tilesN = N >> 4;
    const int tm = wid / tilesN;
    const int tn = wid - tm * tilesN;
    const int r15  = lane & 15;
    const int quad = lane >> 4;

    const float* xp = X + (size_t)(tm * 16 + r15) * K + quad * 8;
    const float* wp = W + (size_t)(tn * 16 + r15) * K + quad * 8;

    float4_t acc = {0.f, 0.f, 0.f, 0.f};
    for (int k0 = 0; k0 < K; k0 += 32) {
        float4 a0 = *(const float4*)(xp + k0);
        float4 a1 = *(const float4*)(xp + k0 + 4);
        float4 b0 = *(const float4*)(wp + k0);
        float4 b1 = *(const float4*)(wp + k0 + 4);
        acc = __builtin_amdgcn_mfma_f32_16x16x32_bf16(pack8(a0, a1), pack8(b0, b1), acc, 0, 0, 0);
    }
    const int col  = tn * 16 + r15;
    const float bias = B[col];
    const int row0 = tm * 16 + quad * 4;
    #pragma unroll
    for (int r = 0; r < 4; ++r)
        Out[(size_t)(row0 + r) * N + col] = f2bf((acc[r] + bias) * scale);
}

__global__ __launch_bounds__(256) void gemm_bf16in_f32out(
    const ushort* __restrict__ X, const float* __restrict__ W,
    const float* __restrict__ B, float* __restrict__ Out,
    int M, int N, int K)
{
    const int lane = threadIdx.x & 63;
    const int wid  = (blockIdx.x * blockDim.x + threadIdx.x) >> 6;
    const int tilesN = N >> 4;
    const int tm = wid / tilesN;
    const int tn = wid - tm * tilesN;
    const int r15  = lane & 15;
    const int quad = lane >> 4;

    const ushort* xp = X + (size_t)(tm * 16 + r15) * K + quad * 8;
    const float*  wp = W + (size_t)(tn * 16 + r15) * K + quad * 8;

    float4_t acc = {0.f, 0.f, 0.f, 0.f};
    for (int k0 = 0; k0 < K; k0 += 32) {
        short8 a = *(const short8*)(xp + k0);
        float4 b0 = *(const float4*)(wp + k0);
        float4 b1 = *(const float4*)(wp + k0 + 4);
        acc = __builtin_amdgcn_mfma_f32_16x16x32_bf16(a, pack8(b0, b1), acc, 0, 0, 0);
    }
    const int col  = tn * 16 + r15;
    const float bias = B[col];
    const int row0 = tm * 16 + quad * 4;
    #pragma unroll
    for (int r = 0; r < 4; ++r)
        Out[(size_t)(row0 + r) * N + col] = acc[r] + bias;
}

// ---------------------------------------------------------------------------
// Flash attention — r21: ONE 512-thread block per (bh, 256-q tile).
// 8 waves x 32 q-rows; grid 256 (1 block/CU, 8 waves = 2/SIMD — same
// occupancy as the old 2x256-thr blocks, but stage/Mb/Q traffic done once
// per CU-tile). Body = proven r12 pipeline (K dbuf + V quad-buf, unroll-4
// cross-tile S||PV). Staging: 1 K-chunk + 1 V-chunk per thread (a0 0..63).
// XCD decode: 4 bh x 8 qt per XCD.
// ---------------------------------------------------------------------------
__global__ __launch_bounds__(512, 2) void flash_attn(
    const ushort* __restrict__ Qb, const ushort* __restrict__ Kb,
    const ushort* __restrict__ Vt, const int* __restrict__ mask,
    ushort* __restrict__ Cb)
{
    __shared__ __align__(16) ushort Ks[2][64][64];  // K tiles, buf = tile&1
    __shared__ __align__(16) ushort Vs[4][64][64];  // V tiles, buf = tile&3
    __shared__ __align__(16) float  Mb[QLEN];       // additive mask bias

    const int tid  = threadIdx.x;         // 0..511
    const int w    = tid >> 6;            // 0..7
    const int lane = tid & 63;
    const int r15  = lane & 15;
    const int quad = lane >> 4;
    const int flat = blockIdx.x;          // 0..255
    const int xcd  = flat & 7;
    const int j    = flat >> 3;           // 0..31
    const int bh   = xcd + 8 * (j >> 3);  // 4 bh per XCD
    const int qt   = j & 7;               // 256-q tile within bh
    const int b = bh >> 4, h = bh & 15;

    {   // mask bias staging: 512 threads x int4
        const int4* m4 = (const int4*)(mask + b * QLEN);
        int4 mv = m4[tid];
        float4 o;
        o.x = mv.x ? 0.f : -INFINITY;
        o.y = mv.y ? 0.f : -INFINITY;
        o.z = mv.z ? 0.f : -INFINITY;
        o.w = mv.w ? 0.f : -INFINITY;
        *(float4*)&Mb[tid * 4] = o;
    }

    // Q B-frags (persistent)
    const int qbase = qt * 256 + w * 32;
    const ushort* qp = Qb + (size_t)(b * QLEN + qbase + r15) * DIM + h * DH + quad * 8;
    short8 qf[2][2];
    qf[0][0] = *(const short8*)(qp);
    qf[0][1] = *(const short8*)(qp + 32);
    qf[1][0] = *(const short8*)(qp + 16 * DIM);
    qf[1][1] = *(const short8*)(qp + 16 * DIM + 32);

    const ushort* kg = Kb + (size_t)b * QLEN * DIM + h * DH;
    const ushort* vg = Vt + (size_t)bh * DH * QLEN;

    // staging coords: 1 K-chunk + 1 V-chunk per thread; a0 = 0..63
    const int a0 = tid >> 3, seg = tid & 7;
    const int a5 = a0 & 31;
    const int krow0 = (a0 & 32)
                    | ((((a5 & 7) >> 2) << 4) + (((a5 >> 3) & 3) << 2) + (a5 & 3));
    const int sK = (seg ^ (krow0 & 7)) << 3;   // +32 bit doesn't affect &7
    const int sV = (seg ^ (a0 & 7)) << 3;
    const int xq = (quad ^ (r15 & 7)) << 3;

    float4_t o[2][4];
    float4_t ol[2];
    #pragma unroll
    for (int rg = 0; rg < 2; ++rg) {
        ol[rg] = (float4_t){0.f, 0.f, 0.f, 0.f};
        #pragma unroll
        for (int ds = 0; ds < 4; ++ds)
            o[rg][ds] = (float4_t){0.f, 0.f, 0.f, 0.f};
    }
    short8 ones8;
    #pragma unroll
    for (int i = 0; i < 8; ++i) ones8[i] = (short)0x3F80;   // bf16 1.0

    uint4 kr0, vr0;    // staging registers (one tile in flight)
    int pkA[4][2][2], pkB[4][2][2];

#define LOAD_TILE(KT) do {                                                    \
    kr0 = *(const uint4*)(kg + (size_t)((KT) + a0) * DIM  + seg * 8);         \
    vr0 = *(const uint4*)(vg + (size_t)a0 * QLEN + (KT) + seg * 8);           \
} while (0)

#define STORE_TILE(KBUF, VBUF) do {                                           \
    *(uint4*)&Ks[KBUF][krow0][sK] = kr0;                                      \
    *(uint4*)&Vs[VBUF][a0   ][sV] = vr0;                                      \
} while (0)

#define S_PHASE(KBUF, KT, PK) do {                                            \
    _Pragma("unroll")                                                         \
    for (int ks = 0; ks < 4; ++ks) {                                          \
        const ushort* krow = &Ks[KBUF][ks * 16 + r15][0];                     \
        short8 kf0 = *(const short8*)(krow + xq);                             \
        short8 kf1 = *(const short8*)(krow + (xq ^ 32));                      \
        const float4 mb = *(const float4*)&Mb[(KT) + ((ks >> 1) << 5)         \
                                              + (quad << 3) + ((ks & 1) << 2)]; \
        _Pragma("unroll")                                                     \
        for (int rg = 0; rg < 2; ++rg) {                                      \
            float4_t s = {0.f, 0.f, 0.f, 0.f};                                \
            s = __builtin_amdgcn_mfma_f32_16x16x32_bf16(kf0, qf[rg][0], s, 0, 0, 0); \
            s = __builtin_amdgcn_mfma_f32_16x16x32_bf16(kf1, qf[rg][1], s, 0, 0, 0); \
            unsigned u0 = __float_as_uint(__builtin_amdgcn_exp2f(s[0] + mb.x)); \
            unsigned u1 = __float_as_uint(__builtin_amdgcn_exp2f(s[1] + mb.y)); \
            unsigned u2 = __float_as_uint(__builtin_amdgcn_exp2f(s[2] + mb.z)); \
            unsigned u3 = __float_as_uint(__builtin_amdgcn_exp2f(s[3] + mb.w)); \
            PK[ks][rg][0] = __builtin_amdgcn_perm(u1, u0, 0x07060302);        \
            PK[ks][rg][1] = __builtin_amdgcn_perm(u3, u2, 0x07060302);        \
        }                                                                     \
    }                                                                         \
} while (0)

#define PV_PHASE(VBUF, PK) do {                                               \
    _Pragma("unroll")                                                         \
    for (int ck = 0; ck < 2; ++ck) {                                          \
        short8 vf[4];                                                         \
        _Pragma("unroll")                                                     \
        for (int ds = 0; ds < 4; ++ds)                                        \
            vf[ds] = *(const short8*)(&Vs[VBUF][ds * 16 + r15][0] + (xq ^ (ck << 5))); \
        _Pragma("unroll")                                                     \
        for (int rg = 0; rg < 2; ++rg) {                                      \
            int4_t pfi = { PK[2 * ck][rg][0], PK[2 * ck][rg][1],              \
                           PK[2 * ck + 1][rg][0], PK[2 * ck + 1][rg][1] };    \
            short8 pf = __builtin_bit_cast(short8, pfi);                      \
            _Pragma("unroll")                                                 \
            for (int ds = 0; ds < 4; ++ds)                                    \
                o[rg][ds] = __builtin_amdgcn_mfma_f32_16x16x32_bf16(          \
                    pf, vf[ds], o[rg][ds], 0, 0, 0);                          \
            ol[rg] = __builtin_amdgcn_mfma_f32_16x16x32_bf16(                 \
                pf, ones8, ol[rg], 0, 0, 0);                                  \
        }                                                                     \
    }                                                                         \
} while (0)

    // ---- prologue: stage tiles 0,1; S_0 -> pkA; prefetch tile 2 ----
    LOAD_TILE(0);
    STORE_TILE(0, 0);
    LOAD_TILE(64);
    __syncthreads();                 // Mb + tile0 visible
    S_PHASE(0, 0, pkA);
    STORE_TILE(1, 1);
    __syncthreads();                 // tile1 visible
    LOAD_TILE(128);

    // ---- main loop: steps t=0..27 (PV_t || S_{t+1}), unroll-4 ----
    for (int kb = 0; kb < 1792; kb += 256) {
        // t = kb/64 + 0   (t&3 == 0)
        S_PHASE(1, kb + 64, pkB);  PV_PHASE(0, pkA);
        STORE_TILE(0, 2); __syncthreads(); LOAD_TILE(kb + 192);
        // t+1             (t&3 == 1)
        S_PHASE(0, kb + 128, pkA); PV_PHASE(1, pkB);
        STORE_TILE(1, 3); __syncthreads(); LOAD_TILE(kb + 256);
        // t+2             (t&3 == 2)
        S_PHASE(1, kb + 192, pkB); PV_PHASE(2, pkA);
        STORE_TILE(0, 0); __syncthreads(); LOAD_TILE(kb + 320);
        // t+3             (t&3 == 3)
        S_PHASE(0, kb + 256, pkA); PV_PHASE(3, pkB);
        STORE_TILE(1, 1); __syncthreads(); LOAD_TILE(kb + 384);
    }

    // ---- epilogue: steps 28..31 ----
    S_PHASE(1, 1856, pkB); PV_PHASE(0, pkA);
    STORE_TILE(0, 2); __syncthreads(); LOAD_TILE(1984);
    S_PHASE(0, 1920, pkA); PV_PHASE(1, pkB);
    STORE_TILE(1, 3); __syncthreads();
    S_PHASE(1, 1984, pkB); PV_PHASE(2, pkA);
    PV_PHASE(3, pkB);

#undef LOAD_TILE
#undef STORE_TILE
#undef S_PHASE
#undef PV_PHASE

    // ---- epilogue: normalize + write ----
    #pragma unroll
    for (int rg = 0; rg < 2; ++rg) {
        #pragma unroll
        for (int r = 0; r < 4; ++r) {
            const float ir = 1.f / fmaxf(ol[rg][r], 1e-30f);
            const size_t rb = (size_t)(b * QLEN + qbase + rg * 16 + quad * 4 + r) * DIM
                              + h * DH;
            Cb[rb +  0 + r15] = f2bf(o[rg][0][r] * ir);
            Cb[rb + 16 + r15] = f2bf(o[rg][1][r] * ir);
            Cb[rb + 32 + r15] = f2bf(o[rg][2][r] * ir);
            Cb[rb + 48 + r15] = f2bf(o[rg][3][r] * ir);
        }
    }
}

// ---------------------------------------------------------------------------
extern "C" void kernel_launch(void* const* d_in, const int* in_sizes, int n_in,
                              void* d_out, int out_size, void* d_ws, size_t ws_size,
                              hipStream_t stream)
{
    const float* x    = (const float*)d_in[0];
    const int*   mask = (const int*)d_in[1];
    const float* q_w  = (const float*)d_in[2];
    const float* q_b  = (const float*)d_in[3];
    const float* k_w  = (const float*)d_in[4];
    const float* k_b  = (const float*)d_in[5];
    const float* v_w  = (const float*)d_in[6];
    const float* v_b  = (const float*)d_in[7];
    const float* o_w  = (const float*)d_in[8];
    const float* o_b  = (const float*)d_in[9];
    float* out = (float*)d_out;

    const size_t SEG = (size_t)MTOK * DIM;        // 4M elements (8 MB bf16)
    ushort* Qbf = (ushort*)d_out;                 // d_out[0:8MB]
    ushort* Xbf = Qbf + SEG;                      // d_out[8:16MB]
    ushort* Kb  = (ushort*)d_ws;                  // ws[0:8MB]
    ushort* Cb  = Kb + SEG;                       // ws[8:16MB]
    ushort* Vt  = Cb + SEG;                       // ws[16:24MB]
    ushort* Wbf = Vt + SEG;                       // ws[24:32MB]

    const bool big = ws_size >= (size_t)32 * 1024 * 1024;

    if (big) {
        conv_all<<<8192, 256, 0, stream>>>(x, q_w, k_w, v_w, o_w, Xbf, Wbf);
        gemm_qkv<<<(MTOK / 256) * (3072 / 192), 512, 0, stream>>>(
            Xbf, Wbf, q_b, k_b, v_b, Qbf, Kb, Vt);
        flash_attn<<<(QLEN / 256) * (BS * NH), 512, 0, stream>>>(Qbf, Kb, Vt, mask, Cb);
        gemm_o<<<(MTOK / 256) * (DIM / 64), 512, 0, stream>>>(
            Cb, Wbf + 3 * (size_t)(DIM * DIM), o_b, out);
    } else {
        const int tiles   = (MTOK / 16) * (DIM / 16);
        const int gblocks = tiles / 4;
        gemm_f32in_bf16out<<<gblocks, 256, 0, stream>>>(x, q_w, q_b, Qbf, MTOK, DIM, DIM, QSCALE);
        gemm_f32in_bf16out<<<gblocks, 256, 0, stream>>>(x, k_w, k_b, Kb,  MTOK, DIM, DIM, 1.0f);
        gemm_f32in_bf16out<<<gblocks, 256, 0, stream>>>(x, v_w, v_b, Cb,  MTOK, DIM, DIM, 1.0f);
        transpose_v<<<dim3(QLEN / 64, BS * NH), 256, 0, stream>>>(Cb, Vt);
        flash_attn<<<(QLEN / 256) * (BS * NH), 512, 0, stream>>>(Qbf, Kb, Vt, mask, Cb);
        gemm_bf16in_f32out<<<tiles / 4, 256, 0, stream>>>(Cb, o_w, o_b, out, MTOK, DIM, DIM);
    }
}

// Round 12
// 185.126 us; speedup vs baseline: 1.0110x; 1.0110x over previous
//
#include <hip/hip_runtime.h>

// ---------------------------------------------------------------------------
// MultiHeadAttention — fp32 in/out, bf16 compute.
// Round 22: gemm_o reverted to the proven r12 2-phase 128x64 form. r21's
// 256x64 4-phase port regressed ~+4us (halved per-wave MFMA per barrier
// phase at unchanged occupancy -> more exposed latency per FLOP; the
// 4-phase schedule pays only with wide-N tiles, cf. qkv's 256x192).
// flash keeps r21 merged 512-thr block (48.1 -> 44.0us, FETCH 69.8 -> 12.4MB
// via XCD decode); qkv keeps r20 256x192 4-phase + B-hoist; conv unchanged.
// BS=2, QLEN=2048, DIM=1024, NH=16, DH=64.
// d_out (16 MB fp32): [ Q_bf16 8MB | X_bf16 8MB ]  (dead before O-GEMM writes)
// d_ws  (>=32MB):     [ K_bf16 8MB | C_bf16 8MB | Vt 8MB | W_bf16 8MB ]
// ---------------------------------------------------------------------------

#define BS    2
#define QLEN  2048
#define DIM   1024
#define NH    16
#define DH    64
#define MTOK  (BS * QLEN)          // 4096 token rows

// Q projection scale: (1/8) * log2(e) so attention uses exp2 directly.
#define QSCALE 0.18033688011112042f

typedef __attribute__((ext_vector_type(8))) short short8;   // 8 bf16
typedef __attribute__((ext_vector_type(4))) float float4_t; // MFMA acc
typedef __attribute__((ext_vector_type(4))) int   int4_t;

__device__ __forceinline__ ushort f2bf(float f) {   // RNE
    unsigned u = __float_as_uint(f);
    return (ushort)((u + 0x7fffu + ((u >> 16) & 1u)) >> 16);
}
__device__ __forceinline__ short8 pack8(float4 a0, float4 a1) {
    short8 r;
    r[0] = (short)f2bf(a0.x); r[1] = (short)f2bf(a0.y);
    r[2] = (short)f2bf(a0.z); r[3] = (short)f2bf(a0.w);
    r[4] = (short)f2bf(a1.x); r[5] = (short)f2bf(a1.y);
    r[6] = (short)f2bf(a1.z); r[7] = (short)f2bf(a1.w);
    return r;
}

// async global->LDS, 16 B per lane (lds dest = wave-uniform base + lane*16).
__device__ __forceinline__ void glds16(const void* g, void* l) {
    __builtin_amdgcn_global_load_lds(
        (const __attribute__((address_space(1))) unsigned int*)g,
        (__attribute__((address_space(3))) unsigned int*)l, 16, 0, 0);
}

// ---------------------------------------------------------------------------
// Combined fp32 -> bf16 convert: X (4M) + 4 weights (1M each), one launch.
// ---------------------------------------------------------------------------
__global__ __launch_bounds__(256) void conv_all(
    const float* __restrict__ x,  const float* __restrict__ qw,
    const float* __restrict__ kw, const float* __restrict__ vw,
    const float* __restrict__ ow,
    ushort* __restrict__ Xbf, ushort* __restrict__ Wbf)
{
    const int blk = blockIdx.x;
    const float* s; ushort* d; size_t base;
    if (blk < 4096)      { s = x;  d = Xbf;             base = (size_t)blk * 1024; }
    else if (blk < 5120) { s = qw; d = Wbf;             base = (size_t)(blk - 4096) * 1024; }
    else if (blk < 6144) { s = kw; d = Wbf + 1048576;   base = (size_t)(blk - 5120) * 1024; }
    else if (blk < 7168) { s = vw; d = Wbf + 2097152;   base = (size_t)(blk - 6144) * 1024; }
    else                 { s = ow; d = Wbf + 3145728;   base = (size_t)(blk - 7168) * 1024; }
    const size_t i = base + threadIdx.x * 4;
    float4 v = *(const float4*)(s + i);
    ushort4 o;
    o.x = f2bf(v.x); o.y = f2bf(v.y); o.z = f2bf(v.z); o.w = f2bf(v.w);
    *(ushort4*)(d + i) = o;
}

// ---------------------------------------------------------------------------
// V transpose (FALLBACK PATH ONLY)
// ---------------------------------------------------------------------------
__global__ __launch_bounds__(256) void transpose_v(
    const ushort* __restrict__ Vrow, ushort* __restrict__ Vt)
{
    __shared__ ushort T[64][72];
    const int tid  = threadIdx.x;
    const int tile = blockIdx.x;
    const int bh   = blockIdx.y;
    const int b = bh >> 4, h = bh & 15;

    #pragma unroll
    for (int rep = 0; rep < 2; ++rep) {
        int ch = tid + rep * 256;
        int tok = ch >> 3, seg = ch & 7;
        uint4 v = *(const uint4*)(Vrow + (size_t)(b * QLEN + tile * 64 + tok) * DIM
                                        + h * DH + seg * 8);
        *(uint4*)&T[tok][seg * 8] = v;
    }
    __syncthreads();
    #pragma unroll
    for (int rep = 0; rep < 2; ++rep) {
        int ch = tid + rep * 256;
        int dim = ch >> 3, tseg = ch & 7;
        ushort t0 = T[tseg * 8 + 0][dim], t1 = T[tseg * 8 + 1][dim];
        ushort t2 = T[tseg * 8 + 2][dim], t3 = T[tseg * 8 + 3][dim];
        ushort t4 = T[tseg * 8 + 4][dim], t5 = T[tseg * 8 + 5][dim];
        ushort t6 = T[tseg * 8 + 6][dim], t7 = T[tseg * 8 + 7][dim];
        uint4 o;
        o.x = (unsigned)t0 | ((unsigned)t1 << 16);
        o.y = (unsigned)t2 | ((unsigned)t3 << 16);
        o.z = (unsigned)t4 | ((unsigned)t5 << 16);
        o.w = (unsigned)t6 | ((unsigned)t7 << 16);
        *(uint4*)(Vt + (size_t)bh * DH * QLEN + (size_t)dim * QLEN
                      + tile * 64 + tseg * 8) = o;
    }
}

// ---------------------------------------------------------------------------
// QKV GEMM — 256x192 tile, BK=64, 4-phase schedule, B-frag hoisting.
// (unchanged from r20)
// ---------------------------------------------------------------------------
__global__ __launch_bounds__(512, 2) void gemm_qkv(
    const ushort* __restrict__ A, const ushort* __restrict__ Bw,
    const float* __restrict__ bias0, const float* __restrict__ bias1,
    const float* __restrict__ bias2,
    ushort* __restrict__ outQ, ushort* __restrict__ outK, ushort* __restrict__ outVt)
{
    __shared__ ushort As[2][256 * 64];   // 32KB per buf
    __shared__ ushort Bs[2][192 * 64];   // 24KB per buf

    const int tid  = threadIdx.x;          // 0..511
    const int w    = tid >> 6;             // 0..7
    const int lane = tid & 63;
    const int r15  = lane & 15;
    const int quad = lane >> 4;
    const int wm   = w >> 2;               // 0..1 (M half, 128 rows)
    const int wn   = w & 3;                // 0..3 (N block, 48 cols)
    const int xg   = r15 & 7;

    const int xcd = blockIdx.x & 7;
    const int lid = blockIdx.x >> 3;               // 0..31
    const int brow = (xcd & 3) * 4 + (lid & 3);    // 0..15
    const int bcol = (xcd >> 2) * 8 + (lid >> 2);  // 0..15
    const int K = DIM;

    float4_t acc[8][3];
    #pragma unroll
    for (int i = 0; i < 8; ++i)
        #pragma unroll
        for (int j = 0; j < 3; ++j)
            acc[i][j] = (float4_t){0.f, 0.f, 0.f, 0.f};

    const ushort* gaS[4];
    const ushort* gbS[3];
    #pragma unroll
    for (int rep = 0; rep < 4; ++rep) {
        const int c   = rep * 512 + tid;           // 0..2047
        const int row = c >> 3;                    // 0..255
        const int g   = (c & 7) ^ (row & 7);
        gaS[rep] = A + (size_t)(brow * 256 + row) * K + g * 8;
    }
    #pragma unroll
    for (int rep = 0; rep < 3; ++rep) {
        const int c   = rep * 512 + tid;           // 0..1535
        const int row = c >> 3;                    // 0..191
        const int g   = (c & 7) ^ (row & 7);
        gbS[rep] = Bw + (size_t)(bcol * 192 + row) * K + g * 8;
    }

    short8 afr[2][4];
    short8 bfr[2][3];

#define QBAR() do { asm volatile("" ::: "memory");                            \
                    __builtin_amdgcn_s_barrier();                             \
                    asm volatile("" ::: "memory"); } while (0)
#define QVM0() asm volatile("s_waitcnt vmcnt(0)" ::: "memory")

#define STAGE_T(BUFI, KOFF) do {                                              \
    _Pragma("unroll")                                                         \
    for (int rep = 0; rep < 4; ++rep)                                         \
        glds16(gaS[rep] + (KOFF), &As[BUFI][(rep * 512 + tid) * 8]);          \
    _Pragma("unroll")                                                         \
    for (int rep = 0; rep < 3; ++rep)                                         \
        glds16(gbS[rep] + (KOFF), &Bs[BUFI][(rep * 512 + tid) * 8]);          \
} while (0)

#define PH_B(BUFI) do {                                                       \
    _Pragma("unroll")                                                         \
    for (int hh = 0; hh < 2; ++hh) {                                          \
        const int ph = ((hh * 4 + quad) ^ xg) * 8;                            \
        _Pragma("unroll")                                                     \
        for (int ns = 0; ns < 3; ++ns)                                        \
            bfr[hh][ns] = *(const short8*)&Bs[BUFI][(wn * 48 + ns * 16 + r15) * 64 + ph]; \
    }                                                                         \
} while (0)

#define PH_A(BUFI, MH) do {                                                   \
    const int arow0 = wm * 128 + (MH) * 64;                                   \
    _Pragma("unroll")                                                         \
    for (int hh = 0; hh < 2; ++hh) {                                          \
        const int ph = ((hh * 4 + quad) ^ xg) * 8;                            \
        _Pragma("unroll")                                                     \
        for (int ms = 0; ms < 4; ++ms)                                        \
            afr[hh][ms] = *(const short8*)&As[BUFI][(arow0 + ms * 16 + r15) * 64 + ph]; \
    }                                                                         \
} while (0)

#define MFMA_MH(MH) do {                                                      \
    __builtin_amdgcn_s_setprio(1);                                            \
    _Pragma("unroll")                                                         \
    for (int hh = 0; hh < 2; ++hh)                                            \
        _Pragma("unroll")                                                     \
        for (int ms = 0; ms < 4; ++ms)                                        \
            _Pragma("unroll")                                                 \
            for (int ns = 0; ns < 3; ++ns)                                    \
                acc[(MH) * 4 + ms][ns] =                                      \
                    __builtin_amdgcn_mfma_f32_16x16x32_bf16(                  \
                        afr[hh][ms], bfr[hh][ns], acc[(MH) * 4 + ms][ns], 0, 0, 0); \
    __builtin_amdgcn_s_setprio(0);                                            \
} while (0)

#define QITER(KB, LAST) do {                                                  \
    STAGE_T(1, (KB) + 64);                                                    \
    PH_B(0); PH_A(0, 0); MFMA_MH(0);                 QBAR();                  \
    PH_A(0, 1); MFMA_MH(1); QVM0();                  QBAR();                  \
    if (!(LAST)) STAGE_T(0, (KB) + 128);                                      \
    PH_B(1); PH_A(1, 0); MFMA_MH(0);                 QBAR();                  \
    PH_A(1, 1); MFMA_MH(1); if (!(LAST)) { QVM0(); } QBAR();                  \
} while (0)

    STAGE_T(0, 0);
    QVM0();
    QBAR();

    for (int i = 0; i < 7; ++i)
        QITER(i * 128, 0);
    QITER(896, 1);

#undef QITER
#undef MFMA_MH
#undef PH_A
#undef PH_B
#undef STAGE_T
#undef QVM0
#undef QBAR

    #pragma unroll
    for (int msg = 0; msg < 8; ++msg) {
        const int rowg = brow * 256 + wm * 128 + msg * 16 + quad * 4;  // token
        #pragma unroll
        for (int nsg = 0; nsg < 3; ++nsg) {
            const int colg = bcol * 192 + wn * 48 + nsg * 16 + r15;
            if (colg < 1024) {
                const float bb = bias0[colg];
                #pragma unroll
                for (int r = 0; r < 4; ++r)
                    outQ[(size_t)(rowg + r) * 1024 + colg] =
                        f2bf((acc[msg][nsg][r] + bb) * QSCALE);
            } else if (colg < 2048) {
                const float bb = bias1[colg - 1024];
                #pragma unroll
                for (int r = 0; r < 4; ++r)
                    outK[(size_t)(rowg + r) * 1024 + (colg - 1024)] =
                        f2bf(acc[msg][nsg][r] + bb);
            } else {
                const int vcol = colg - 2048;
                const int hh2 = vcol >> 6, dd = vcol & 63;
                const float bb = bias2[vcol];
                const int bidx = rowg >> 11;
                const int tloc = rowg & 2047;
                ushort4 o4;
                o4.x = f2bf(acc[msg][nsg][0] + bb);
                o4.y = f2bf(acc[msg][nsg][1] + bb);
                o4.z = f2bf(acc[msg][nsg][2] + bb);
                o4.w = f2bf(acc[msg][nsg][3] + bb);
                *(ushort4*)&outVt[((size_t)(bidx * 16 + hh2) * 64 + dd) * QLEN + tloc] = o4;
            }
        }
    }
}

// ---------------------------------------------------------------------------
// O-projection GEMM: 128x64 tile, BK=64 double-buffered, __syncthreads
// 2-phase (proven r12 form; r21's 256x64 4-phase port regressed +4us).
// ---------------------------------------------------------------------------
__global__ __launch_bounds__(256) void gemm_o(
    const ushort* __restrict__ A, const ushort* __restrict__ Bw,
    const float* __restrict__ bias, float* __restrict__ Out)
{
    __shared__ ushort As[2][128 * 64];   // 16KB each buf
    __shared__ ushort Bs[2][64 * 64];    // 8KB each buf
    const int tid  = threadIdx.x;
    const int w    = tid >> 6;
    const int lane = tid & 63;
    const int r15  = lane & 15;
    const int quad = lane >> 4;
    const int xcd = blockIdx.x & 7;
    const int lid = blockIdx.x >> 3;               // 0..63
    const int brow = (xcd & 3) * 8 + (lid & 7);    // 0..31
    const int bcol = (xcd >> 2) * 8 + (lid >> 3);  // 0..15
    const int wrow = w * 32;
    const int K = DIM;

    float4_t acc[2][4];
    #pragma unroll
    for (int i = 0; i < 2; ++i)
        #pragma unroll
        for (int j = 0; j < 4; ++j)
            acc[i][j] = (float4_t){0.f, 0.f, 0.f, 0.f};

    int chA[4];  const ushort* gaS[4];
    #pragma unroll
    for (int rep = 0; rep < 4; ++rep) {
        const int ch  = w * 256 + rep * 64 + lane;
        const int row = ch >> 3;
        const int g   = (ch & 7) ^ (row & 7);
        chA[rep] = ch;
        gaS[rep] = A + (size_t)(brow * 128 + row) * K + g * 8;
    }
    int chB[2];  const ushort* gbS[2];
    #pragma unroll
    for (int rep = 0; rep < 2; ++rep) {
        const int ch  = w * 128 + rep * 64 + lane;
        const int row = ch >> 3;
        const int g   = (ch & 7) ^ (row & 7);
        chB[rep] = ch;
        gbS[rep] = Bw + (size_t)(bcol * 64 + row) * K + g * 8;
    }
    const int xg = r15 & 7;

    #pragma unroll
    for (int rep = 0; rep < 4; ++rep)
        glds16(gaS[rep], &As[0][chA[rep] * 8]);
    #pragma unroll
    for (int rep = 0; rep < 2; ++rep)
        glds16(gbS[rep], &Bs[0][chB[rep] * 8]);
    __syncthreads();

    int p = 0;
    for (int k0 = 0; k0 < K; k0 += 64) {
        if (k0 + 64 < K) {
            #pragma unroll
            for (int rep = 0; rep < 4; ++rep)
                glds16(gaS[rep] + k0 + 64, &As[p ^ 1][chA[rep] * 8]);
            #pragma unroll
            for (int rep = 0; rep < 2; ++rep)
                glds16(gbS[rep] + k0 + 64, &Bs[p ^ 1][chB[rep] * 8]);
        }
        #pragma unroll
        for (int hh = 0; hh < 2; ++hh) {
            const int ph = ((hh * 4 + quad) ^ xg) * 8;
            short8 af[2], bf[4];
            #pragma unroll
            for (int ms = 0; ms < 2; ++ms)
                af[ms] = *(const short8*)&As[p][(wrow + ms * 16 + r15) * 64 + ph];
            #pragma unroll
            for (int ns = 0; ns < 4; ++ns)
                bf[ns] = *(const short8*)&Bs[p][(ns * 16 + r15) * 64 + ph];
            #pragma unroll
            for (int ms = 0; ms < 2; ++ms)
                #pragma unroll
                for (int ns = 0; ns < 4; ++ns)
                    acc[ms][ns] = __builtin_amdgcn_mfma_f32_16x16x32_bf16(
                        af[ms], bf[ns], acc[ms][ns], 0, 0, 0);
        }
        __syncthreads();
        p ^= 1;
    }

    #pragma unroll
    for (int ms = 0; ms < 2; ++ms) {
        const int rowg = brow * 128 + wrow + ms * 16 + quad * 4;
        #pragma unroll
        for (int ns = 0; ns < 4; ++ns) {
            const int colg = bcol * 64 + ns * 16 + r15;
            const float bb = bias[colg];
            #pragma unroll
            for (int r = 0; r < 4; ++r)
                Out[(size_t)(rowg + r) * 1024 + colg] = acc[ms][ns][r] + bb;
        }
    }
}

// ---------------------------------------------------------------------------
// Fallback GEMMs (fp32 inputs, 16x16/wave) for ws_size < 32MB.
// ---------------------------------------------------------------------------
__global__ __launch_bounds__(256) void gemm_f32in_bf16out(
    const float* __restrict__ X, const float* __restrict__ W,
    const float* __restrict__ B, ushort* __restrict__ Out,
    int M, int N, int K, float scale)
{
    const int lane = threadIdx.x & 63;
    const int wid  = (blockIdx.x * blockDim.x + threadIdx.x) >> 6;
    const int tilesN = N >> 4;
    const int tm = wid / tilesN;
    const int tn = wid - tm * tilesN;
    const int r15  = lane & 15;
    const int quad = lane >> 4;

    const float* xp = X + (size_t)(tm * 16 + r15) * K + quad * 8;
    const float* wp = W + (size_t)(tn * 16 + r15) * K + quad * 8;

    float4_t acc = {0.f, 0.f, 0.f, 0.f};
    for (int k0 = 0; k0 < K; k0 += 32) {
        float4 a0 = *(const float4*)(xp + k0);
        float4 a1 = *(const float4*)(xp + k0 + 4);
        float4 b0 = *(const float4*)(wp + k0);
        float4 b1 = *(const float4*)(wp + k0 + 4);
        acc = __builtin_amdgcn_mfma_f32_16x16x32_bf16(pack8(a0, a1), pack8(b0, b1), acc, 0, 0, 0);
    }
    const int col  = tn * 16 + r15;
    const float bias = B[col];
    const int row0 = tm * 16 + quad * 4;
    #pragma unroll
    for (int r = 0; r < 4; ++r)
        Out[(size_t)(row0 + r) * N + col] = f2bf((acc[r] + bias) * scale);
}

__global__ __launch_bounds__(256) void gemm_bf16in_f32out(
    const ushort* __restrict__ X, const float* __restrict__ W,
    const float* __restrict__ B, float* __restrict__ Out,
    int M, int N, int K)
{
    const int lane = threadIdx.x & 63;
    const int wid  = (blockIdx.x * blockDim.x + threadIdx.x) >> 6;
    const int tilesN = N >> 4;
    const int tm = wid / tilesN;
    const int tn = wid - tm * tilesN;
    const int r15  = lane & 15;
    const int quad = lane >> 4;

    const ushort* xp = X + (size_t)(tm * 16 + r15) * K + quad * 8;
    const float*  wp = W + (size_t)(tn * 16 + r15) * K + quad * 8;

    float4_t acc = {0.f, 0.f, 0.f, 0.f};
    for (int k0 = 0; k0 < K; k0 += 32) {
        short8 a = *(const short8*)(xp + k0);
        float4 b0 = *(const float4*)(wp + k0);
        float4 b1 = *(const float4*)(wp + k0 + 4);
        acc = __builtin_amdgcn_mfma_f32_16x16x32_bf16(a, pack8(b0, b1), acc, 0, 0, 0);
    }
    const int col  = tn * 16 + r15;
    const float bias = B[col];
    const int row0 = tm * 16 + quad * 4;
    #pragma unroll
    for (int r = 0; r < 4; ++r)
        Out[(size_t)(row0 + r) * N + col] = acc[r] + bias;
}

// ---------------------------------------------------------------------------
// Flash attention — unchanged from r21: ONE 512-thread block per
// (bh, 256-q tile); proven r12 pipeline body; XCD decode.
// ---------------------------------------------------------------------------
__global__ __launch_bounds__(512, 2) void flash_attn(
    const ushort* __restrict__ Qb, const ushort* __restrict__ Kb,
    const ushort* __restrict__ Vt, const int* __restrict__ mask,
    ushort* __restrict__ Cb)
{
    __shared__ __align__(16) ushort Ks[2][64][64];  // K tiles, buf = tile&1
    __shared__ __align__(16) ushort Vs[4][64][64];  // V tiles, buf = tile&3
    __shared__ __align__(16) float  Mb[QLEN];       // additive mask bias

    const int tid  = threadIdx.x;         // 0..511
    const int w    = tid >> 6;            // 0..7
    const int lane = tid & 63;
    const int r15  = lane & 15;
    const int quad = lane >> 4;
    const int flat = blockIdx.x;          // 0..255
    const int xcd  = flat & 7;
    const int j    = flat >> 3;           // 0..31
    const int bh   = xcd + 8 * (j >> 3);  // 4 bh per XCD
    const int qt   = j & 7;               // 256-q tile within bh
    const int b = bh >> 4, h = bh & 15;

    {   // mask bias staging: 512 threads x int4
        const int4* m4 = (const int4*)(mask + b * QLEN);
        int4 mv = m4[tid];
        float4 o;
        o.x = mv.x ? 0.f : -INFINITY;
        o.y = mv.y ? 0.f : -INFINITY;
        o.z = mv.z ? 0.f : -INFINITY;
        o.w = mv.w ? 0.f : -INFINITY;
        *(float4*)&Mb[tid * 4] = o;
    }

    // Q B-frags (persistent)
    const int qbase = qt * 256 + w * 32;
    const ushort* qp = Qb + (size_t)(b * QLEN + qbase + r15) * DIM + h * DH + quad * 8;
    short8 qf[2][2];
    qf[0][0] = *(const short8*)(qp);
    qf[0][1] = *(const short8*)(qp + 32);
    qf[1][0] = *(const short8*)(qp + 16 * DIM);
    qf[1][1] = *(const short8*)(qp + 16 * DIM + 32);

    const ushort* kg = Kb + (size_t)b * QLEN * DIM + h * DH;
    const ushort* vg = Vt + (size_t)bh * DH * QLEN;

    // staging coords: 1 K-chunk + 1 V-chunk per thread; a0 = 0..63
    const int a0 = tid >> 3, seg = tid & 7;
    const int a5 = a0 & 31;
    const int krow0 = (a0 & 32)
                    | ((((a5 & 7) >> 2) << 4) + (((a5 >> 3) & 3) << 2) + (a5 & 3));
    const int sK = (seg ^ (krow0 & 7)) << 3;   // +32 bit doesn't affect &7
    const int sV = (seg ^ (a0 & 7)) << 3;
    const int xq = (quad ^ (r15 & 7)) << 3;

    float4_t o[2][4];
    float4_t ol[2];
    #pragma unroll
    for (int rg = 0; rg < 2; ++rg) {
        ol[rg] = (float4_t){0.f, 0.f, 0.f, 0.f};
        #pragma unroll
        for (int ds = 0; ds < 4; ++ds)
            o[rg][ds] = (float4_t){0.f, 0.f, 0.f, 0.f};
    }
    short8 ones8;
    #pragma unroll
    for (int i = 0; i < 8; ++i) ones8[i] = (short)0x3F80;   // bf16 1.0

    uint4 kr0, vr0;    // staging registers (one tile in flight)
    int pkA[4][2][2], pkB[4][2][2];

#define LOAD_TILE(KT) do {                                                    \
    kr0 = *(const uint4*)(kg + (size_t)((KT) + a0) * DIM  + seg * 8);         \
    vr0 = *(const uint4*)(vg + (size_t)a0 * QLEN + (KT) + seg * 8);           \
} while (0)

#define STORE_TILE(KBUF, VBUF) do {                                           \
    *(uint4*)&Ks[KBUF][krow0][sK] = kr0;                                      \
    *(uint4*)&Vs[VBUF][a0   ][sV] = vr0;                                      \
} while (0)

#define S_PHASE(KBUF, KT, PK) do {                                            \
    _Pragma("unroll")                                                         \
    for (int ks = 0; ks < 4; ++ks) {                                          \
        const ushort* krow = &Ks[KBUF][ks * 16 + r15][0];                     \
        short8 kf0 = *(const short8*)(krow + xq);                             \
        short8 kf1 = *(const short8*)(krow + (xq ^ 32));                      \
        const float4 mb = *(const float4*)&Mb[(KT) + ((ks >> 1) << 5)         \
                                              + (quad << 3) + ((ks & 1) << 2)]; \
        _Pragma("unroll")                                                     \
        for (int rg = 0; rg < 2; ++rg) {                                      \
            float4_t s = {0.f, 0.f, 0.f, 0.f};                                \
            s = __builtin_amdgcn_mfma_f32_16x16x32_bf16(kf0, qf[rg][0], s, 0, 0, 0); \
            s = __builtin_amdgcn_mfma_f32_16x16x32_bf16(kf1, qf[rg][1], s, 0, 0, 0); \
            unsigned u0 = __float_as_uint(__builtin_amdgcn_exp2f(s[0] + mb.x)); \
            unsigned u1 = __float_as_uint(__builtin_amdgcn_exp2f(s[1] + mb.y)); \
            unsigned u2 = __float_as_uint(__builtin_amdgcn_exp2f(s[2] + mb.z)); \
            unsigned u3 = __float_as_uint(__builtin_amdgcn_exp2f(s[3] + mb.w)); \
            PK[ks][rg][0] = __builtin_amdgcn_perm(u1, u0, 0x07060302);        \
            PK[ks][rg][1] = __builtin_amdgcn_perm(u3, u2, 0x07060302);        \
        }                                                                     \
    }                                                                         \
} while (0)

#define PV_PHASE(VBUF, PK) do {                                               \
    _Pragma("unroll")                                                         \
    for (int ck = 0; ck < 2; ++ck) {                                          \
        short8 vf[4];                                                         \
        _Pragma("unroll")                                                     \
        for (int ds = 0; ds < 4; ++ds)                                        \
            vf[ds] = *(const short8*)(&Vs[VBUF][ds * 16 + r15][0] + (xq ^ (ck << 5))); \
        _Pragma("unroll")                                                     \
        for (int rg = 0; rg < 2; ++rg) {                                      \
            int4_t pfi = { PK[2 * ck][rg][0], PK[2 * ck][rg][1],              \
                           PK[2 * ck + 1][rg][0], PK[2 * ck + 1][rg][1] };    \
            short8 pf = __builtin_bit_cast(short8, pfi);                      \
            _Pragma("unroll")                                                 \
            for (int ds = 0; ds < 4; ++ds)                                    \
                o[rg][ds] = __builtin_amdgcn_mfma_f32_16x16x32_bf16(          \
                    pf, vf[ds], o[rg][ds], 0, 0, 0);                          \
            ol[rg] = __builtin_amdgcn_mfma_f32_16x16x32_bf16(                 \
                pf, ones8, ol[rg], 0, 0, 0);                                  \
        }                                                                     \
    }                                                                         \
} while (0)

    // ---- prologue: stage tiles 0,1; S_0 -> pkA; prefetch tile 2 ----
    LOAD_TILE(0);
    STORE_TILE(0, 0);
    LOAD_TILE(64);
    __syncthreads();                 // Mb + tile0 visible
    S_PHASE(0, 0, pkA);
    STORE_TILE(1, 1);
    __syncthreads();                 // tile1 visible
    LOAD_TILE(128);

    // ---- main loop: steps t=0..27 (PV_t || S_{t+1}), unroll-4 ----
    for (int kb = 0; kb < 1792; kb += 256) {
        // t = kb/64 + 0   (t&3 == 0)
        S_PHASE(1, kb + 64, pkB);  PV_PHASE(0, pkA);
        STORE_TILE(0, 2); __syncthreads(); LOAD_TILE(kb + 192);
        // t+1             (t&3 == 1)
        S_PHASE(0, kb + 128, pkA); PV_PHASE(1, pkB);
        STORE_TILE(1, 3); __syncthreads(); LOAD_TILE(kb + 256);
        // t+2             (t&3 == 2)
        S_PHASE(1, kb + 192, pkB); PV_PHASE(2, pkA);
        STORE_TILE(0, 0); __syncthreads(); LOAD_TILE(kb + 320);
        // t+3             (t&3 == 3)
        S_PHASE(0, kb + 256, pkA); PV_PHASE(3, pkB);
        STORE_TILE(1, 1); __syncthreads(); LOAD_TILE(kb + 384);
    }

    // ---- epilogue: steps 28..31 ----
    S_PHASE(1, 1856, pkB); PV_PHASE(0, pkA);
    STORE_TILE(0, 2); __syncthreads(); LOAD_TILE(1984);
    S_PHASE(0, 1920, pkA); PV_PHASE(1, pkB);
    STORE_TILE(1, 3); __syncthreads();
    S_PHASE(1, 1984, pkB); PV_PHASE(2, pkA);
    PV_PHASE(3, pkB);

#undef LOAD_TILE
#undef STORE_TILE
#undef S_PHASE
#undef PV_PHASE

    // ---- epilogue: normalize + write ----
    #pragma unroll
    for (int rg = 0; rg < 2; ++rg) {
        #pragma unroll
        for (int r = 0; r < 4; ++r) {
            const float ir = 1.f / fmaxf(ol[rg][r], 1e-30f);
            const size_t rb = (size_t)(b * QLEN + qbase + rg * 16 + quad * 4 + r) * DIM
                              + h * DH;
            Cb[rb +  0 + r15] = f2bf(o[rg][0][r] * ir);
            Cb[rb + 16 + r15] = f2bf(o[rg][1][r] * ir);
            Cb[rb + 32 + r15] = f2bf(o[rg][2][r] * ir);
            Cb[rb + 48 + r15] = f2bf(o[rg][3][r] * ir);
        }
    }
}

// ---------------------------------------------------------------------------
extern "C" void kernel_launch(void* const* d_in, const int* in_sizes, int n_in,
                              void* d_out, int out_size, void* d_ws, size_t ws_size,
                              hipStream_t stream)
{
    const float* x    = (const float*)d_in[0];
    const int*   mask = (const int*)d_in[1];
    const float* q_w  = (const float*)d_in[2];
    const float* q_b  = (const float*)d_in[3];
    const float* k_w  = (const float*)d_in[4];
    const float* k_b  = (const float*)d_in[5];
    const float* v_w  = (const float*)d_in[6];
    const float* v_b  = (const float*)d_in[7];
    const float* o_w  = (const float*)d_in[8];
    const float* o_b  = (const float*)d_in[9];
    float* out = (float*)d_out;

    const size_t SEG = (size_t)MTOK * DIM;        // 4M elements (8 MB bf16)
    ushort* Qbf = (ushort*)d_out;                 // d_out[0:8MB]
    ushort* Xbf = Qbf + SEG;                      // d_out[8:16MB]
    ushort* Kb  = (ushort*)d_ws;                  // ws[0:8MB]
    ushort* Cb  = Kb + SEG;                       // ws[8:16MB]
    ushort* Vt  = Cb + SEG;                       // ws[16:24MB]
    ushort* Wbf = Vt + SEG;                       // ws[24:32MB]

    const bool big = ws_size >= (size_t)32 * 1024 * 1024;

    if (big) {
        conv_all<<<8192, 256, 0, stream>>>(x, q_w, k_w, v_w, o_w, Xbf, Wbf);
        gemm_qkv<<<(MTOK / 256) * (3072 / 192), 512, 0, stream>>>(
            Xbf, Wbf, q_b, k_b, v_b, Qbf, Kb, Vt);
        flash_attn<<<(QLEN / 256) * (BS * NH), 512, 0, stream>>>(Qbf, Kb, Vt, mask, Cb);
        gemm_o<<<(MTOK / 128) * (DIM / 64), 256, 0, stream>>>(
            Cb, Wbf + 3 * (size_t)(DIM * DIM), o_b, out);
    } else {
        const int tiles   = (MTOK / 16) * (DIM / 16);
        const int gblocks = tiles / 4;
        gemm_f32in_bf16out<<<gblocks, 256, 0, stream>>>(x, q_w, q_b, Qbf, MTOK, DIM, DIM, QSCALE);
        gemm_f32in_bf16out<<<gblocks, 256, 0, stream>>>(x, k_w, k_b, Kb,  MTOK, DIM, DIM, 1.0f);
        gemm_f32in_bf16out<<<gblocks, 256, 0, stream>>>(x, v_w, v_b, Cb,  MTOK, DIM, DIM, 1.0f);
        transpose_v<<<dim3(QLEN / 64, BS * NH), 256, 0, stream>>>(Cb, Vt);
        flash_attn<<<(QLEN / 256) * (BS * NH), 512, 0, stream>>>(Qbf, Kb, Vt, mask, Cb);
        gemm_bf16in_f32out<<<tiles / 4, 256, 0, stream>>>(Cb, o_w, o_b, out, MTOK, DIM, DIM);
    }
}